// Round 3
// baseline (511.149 us; speedup 1.0000x reference)
//
#include <hip/hip_runtime.h>

typedef __attribute__((ext_vector_type(8))) short short8;
typedef __attribute__((ext_vector_type(4))) float f32x4;

static __device__ __forceinline__ float bf2f(unsigned short u) {
    unsigned int x = ((unsigned int)u) << 16;
    union { unsigned int i; float f; } c; c.i = x; return c.f;
}
static __device__ __forceinline__ unsigned short f2bf(float f) {
    union { float f; unsigned int i; } c; c.f = f;
    unsigned int x = c.i;
    unsigned int r = (x + 0x7FFFu + ((x >> 16) & 1u)) >> 16;
    return (unsigned short)r;
}

// ---------------- prepack W [Cout=128][Cin][7] fp32 -> fragment-linear bf16 ----------------
// Wp[( (s*8 + f)*64 + lane )*8 + j] = W[o = f*16+(lane&15)][c = kk%Cin][t = kk/Cin],
// kk = s*32 + 8*(lane>>4) + j
__global__ void prepack_w(const float* __restrict__ W, unsigned short* __restrict__ Wp,
                          int Cin, int S) {
    int tid = blockIdx.x * blockDim.x + threadIdx.x;
    if (tid >= S * 512) return;
    int lane = tid & 63;
    int f = (tid >> 6) & 7;
    int s = tid >> 9;
    int o = f * 16 + (lane & 15);
    int kbase = s * 32 + 8 * (lane >> 4);
    unsigned short* dst = Wp + (size_t)tid * 8;
#pragma unroll
    for (int j = 0; j < 8; ++j) {
        int kk = kbase + j;
        int t = kk / Cin;
        int c = kk - t * Cin;
        dst[j] = f2bf(W[((size_t)o * Cin + c) * 7 + t]);
    }
}

// Same but scales W[o][c][t] by rstd[b][c] (norm folded into conv3), one copy per batch.
__global__ void prepack_w_scaled(const float* __restrict__ W, const float2* __restrict__ stats,
                                 unsigned short* __restrict__ Wp, int Cin, int S) {
    int tid = blockIdx.x * blockDim.x + threadIdx.x;
    if (tid >= 2 * S * 512) return;
    int b = tid / (S * 512);
    int rem = tid - b * S * 512;
    int lane = rem & 63;
    int f = (rem >> 6) & 7;
    int s = rem >> 9;
    int o = f * 16 + (lane & 15);
    int kbase = s * 32 + 8 * (lane >> 4);
    unsigned short* dst = Wp + (size_t)tid * 8;
#pragma unroll
    for (int j = 0; j < 8; ++j) {
        int kk = kbase + j;
        int t = kk / Cin;
        int c = kk - t * Cin;
        float scale = stats[b * 128 + c].y;
        dst[j] = f2bf(W[((size_t)o * Cin + c) * 7 + t] * scale);
    }
}

// b2'[b][o] = b2[o] - sum_{c,t} W2[o][c][t] * rstd[b][c] * mu[b][c]
__global__ void fold_bias2(const float* __restrict__ W2, const float* __restrict__ b2,
                           const float2* __restrict__ stats, float* __restrict__ b2out) {
    int b = blockIdx.x, o = threadIdx.x;
    float sum = 0.f;
    for (int c = 0; c < 128; ++c) {
        float2 st = stats[b * 128 + c];
        float sm = st.x * st.y;
        float ws = 0.f;
#pragma unroll
        for (int t = 0; t < 7; ++t) ws += W2[((size_t)o * 128 + c) * 7 + t];
        sum += ws * sm;
    }
    b2out[b * 128 + o] = b2[o] - sum;
}

// ---------------- transpose fp32 [B][C][N] -> bf16 [B][N][ldo] at column offset ----------------
__global__ void transpose_cast(const float* __restrict__ in, unsigned short* __restrict__ out,
                               int C, int N, int ldo, int coff) {
    __shared__ float tile[32][33];
    int b = blockIdx.z;
    int n0 = blockIdx.x * 32;
    int c0 = blockIdx.y * 32;
    const float* inb = in + (size_t)b * C * N;
    unsigned short* outb = out + (size_t)b * N * ldo;
    int tx = threadIdx.x, ty = threadIdx.y;
#pragma unroll
    for (int i = 0; i < 32; i += 8) {
        int c = c0 + ty + i, n = n0 + tx;
        float v = 0.f;
        if (n < N) v = inb[(size_t)c * N + n];
        tile[ty + i][tx] = v;
    }
    __syncthreads();
#pragma unroll
    for (int i = 0; i < 32; i += 8) {
        int n = n0 + ty + i, c = c0 + tx;
        if (n < N) outb[(size_t)n * ldo + coff + c] = f2bf(tile[tx][ty + i]);
    }
}

// ---------------- gather-conv via MFMA, optional fused per-block stats ----------------
// Block: 64 points x 128 couts, 4 waves. Wave = 32 points (pg=wid&1) x 64 couts (h=wid>>1).
// Waves pg=0 (wid 0,2) gather the same rows -> L1/L2 sharing of the gather traffic.
template<int CS, int LD, bool STATS>
__global__ __launch_bounds__(256, 4) void conv_mfma(
    const unsigned short* __restrict__ src,
    const int* __restrict__ nbrs,
    const unsigned short* __restrict__ Wp, size_t w_bstride8,
    const float* __restrict__ bias, int bias_bstride,
    unsigned short* __restrict__ dst,
    float2* __restrict__ part,
    int N, int coff)
{
    const int lane = threadIdx.x & 63;
    const int wid  = threadIdx.x >> 6;
    const int pg   = wid & 1;    // point-group
    const int h    = wid >> 1;   // cout-half
    const int b    = blockIdx.y;
    const int p_base = blockIdx.x * 64 + pg * 32;
    const int l15 = lane & 15;
    const int ks  = lane >> 4;

    const unsigned short* srcb = src + (size_t)b * N * CS;
    // fold cout-half offset (h*4 f-frags * 64 lanes) into the W base
    const short8* wb = reinterpret_cast<const short8*>(Wp) + (size_t)b * w_bstride8 + (size_t)h * 256;
    const float* biasb = bias + (size_t)b * bias_bstride + h * 64;

    int idx0[7], idx1[7];
    {
        int p0 = p_base + l15;        int pe0 = p0 < N ? p0 : N - 1;
        int p1 = p_base + 16 + l15;   int pe1 = p1 < N ? p1 : N - 1;
        idx0[0] = pe0; idx1[0] = pe1;
        const int* nb0 = nbrs + ((size_t)b * N + pe0) * 6;
        const int* nb1 = nbrs + ((size_t)b * N + pe1) * 6;
#pragma unroll
        for (int t = 1; t < 7; ++t) { idx0[t] = nb0[t - 1]; idx1[t] = nb1[t - 1]; }
    }

    float bias_v[4];
#pragma unroll
    for (int fi = 0; fi < 4; ++fi) bias_v[fi] = biasb[fi * 16 + l15];

    f32x4 acc[2][4];
#pragma unroll
    for (int pf = 0; pf < 2; ++pf)
#pragma unroll
        for (int fi = 0; fi < 4; ++fi) acc[pf][fi] = (f32x4){0.f, 0.f, 0.f, 0.f};

    const int SPT = CS / 32;  // K-steps per tap
#pragma unroll
    for (int t = 0; t < 7; ++t) {
        const unsigned short* row0 = srcb + (size_t)idx0[t] * CS + 8 * ks;
        const unsigned short* row1 = srcb + (size_t)idx1[t] * CS + 8 * ks;
#pragma unroll
        for (int s2 = 0; s2 < SPT; ++s2) {
            const int s = t * SPT + s2;
            short8 a0 = *reinterpret_cast<const short8*>(row0 + s2 * 32);
            short8 a1 = *reinterpret_cast<const short8*>(row1 + s2 * 32);
            const short8* wbase = wb + ((size_t)s * 512 + lane);
#pragma unroll
            for (int fi = 0; fi < 4; ++fi) {
                short8 bfv = wbase[fi * 64];
                acc[0][fi] = __builtin_amdgcn_mfma_f32_16x16x32_bf16(a0, bfv, acc[0][fi], 0, 0, 0);
                acc[1][fi] = __builtin_amdgcn_mfma_f32_16x16x32_bf16(a1, bfv, acc[1][fi], 0, 0, 0);
            }
        }
    }

    unsigned short* dstb = dst + (size_t)b * N * LD + coff + h * 64;
#pragma unroll
    for (int pf = 0; pf < 2; ++pf) {
#pragma unroll
        for (int r = 0; r < 4; ++r) {
            int p = p_base + pf * 16 + ks * 4 + r;
            if (p < N) {
#pragma unroll
                for (int fi = 0; fi < 4; ++fi) {
                    dstb[(size_t)p * LD + fi * 16 + l15] = f2bf(acc[pf][fi][r] + bias_v[fi]);
                }
            }
        }
    }

    if constexpr (STATS) {
        float s[4], q[4];
#pragma unroll
        for (int fi = 0; fi < 4; ++fi) { s[fi] = 0.f; q[fi] = 0.f; }
#pragma unroll
        for (int pf = 0; pf < 2; ++pf) {
#pragma unroll
            for (int r = 0; r < 4; ++r) {
                int p = p_base + pf * 16 + ks * 4 + r;
                if (p < N) {
#pragma unroll
                    for (int fi = 0; fi < 4; ++fi) {
                        float v = acc[pf][fi][r] + bias_v[fi];
                        s[fi] += v; q[fi] += v * v;
                    }
                }
            }
        }
        // combine the 4 ks-groups (different points, same channels)
#pragma unroll
        for (int fi = 0; fi < 4; ++fi) {
            s[fi] += __shfl_xor(s[fi], 16); s[fi] += __shfl_xor(s[fi], 32);
            q[fi] += __shfl_xor(q[fi], 16); q[fi] += __shfl_xor(q[fi], 32);
        }
        __shared__ float shs[4][64], shq[4][64];
        if (lane < 16) {
#pragma unroll
            for (int fi = 0; fi < 4; ++fi) {
                shs[wid][fi * 16 + l15] = s[fi];
                shq[wid][fi * 16 + l15] = q[fi];
            }
        }
        __syncthreads();
        if (threadIdx.x < 128) {
            int c = threadIdx.x;          // channel 0..127
            int hh = c >> 6, cl = c & 63; // waves 2*hh and 2*hh+1 hold this channel-half
            float ss = shs[2 * hh][cl] + shs[2 * hh + 1][cl];
            float qq = shq[2 * hh][cl] + shq[2 * hh + 1][cl];
            part[((size_t)b * gridDim.x + blockIdx.x) * 128 + c] = make_float2(ss, qq);
        }
    }
}

__global__ void stats_final(const float2* __restrict__ part, float2* __restrict__ stats,
                            int N, int NB) {
    int b = blockIdx.x, c = threadIdx.x;
    const float2* p = part + (size_t)b * NB * 128 + c;
    float s = 0.f, sq = 0.f;
    for (int i = 0; i < NB; ++i) { float2 v = p[(size_t)i * 128]; s += v.x; sq += v.y; }
    float mu = s / N;
    float var = sq / N - mu * mu;
    stats[b * 128 + c] = make_float2(mu, rsqrtf(var + 1e-5f));
}

// ---------------- final: out[b][o][n] = (z-mu2)*rstd2 + (x1-mu1)*rstd1, fp32 transposed ----------------
__global__ void final_k(const unsigned short* __restrict__ z, const unsigned short* __restrict__ x1,
                        const float2* __restrict__ stats1, const float2* __restrict__ stats2,
                        float* __restrict__ out, int N) {
    __shared__ float tile[32][33];
    int b = blockIdx.z;
    int n0 = blockIdx.x * 32, o0 = blockIdx.y * 32;
    int tx = threadIdx.x, ty = threadIdx.y;
    const unsigned short* zb = z  + (size_t)b * N * 128;
    const unsigned short* xb = x1 + (size_t)b * N * 128;
    float2 st1 = stats1[b * 128 + o0 + tx];
    float2 st2 = stats2[b * 128 + o0 + tx];
#pragma unroll
    for (int i = 0; i < 32; i += 8) {
        int n = n0 + ty + i;
        float v = 0.f;
        if (n < N) {
            float zv = bf2f(zb[(size_t)n * 128 + o0 + tx]);
            float xv = bf2f(xb[(size_t)n * 128 + o0 + tx]);
            v = (zv - st2.x) * st2.y + (xv - st1.x) * st1.y;
        }
        tile[ty + i][tx] = v;
    }
    __syncthreads();
    float* ob = out + (size_t)b * 128 * N;
#pragma unroll
    for (int i = 0; i < 32; i += 8) {
        int o = o0 + ty + i, n = n0 + tx;
        if (n < N) ob[(size_t)o * N + n] = tile[tx][ty + i];
    }
}

extern "C" void kernel_launch(void* const* d_in, const int* in_sizes, int n_in,
                              void* d_out, int out_size, void* d_ws, size_t ws_size,
                              hipStream_t stream) {
    const float* from_up   = (const float*)d_in[0];  // [2,256,30000]
    const float* from_down = (const float*)d_in[1];  // [2,128,30000]
    const int*   neighbors = (const int*)d_in[2];    // [2,30000,6]
    const float* W_up = (const float*)d_in[3];
    const float* b_up = (const float*)d_in[4];
    const float* W_1  = (const float*)d_in[5];
    const float* b_1  = (const float*)d_in[6];
    const float* W_2  = (const float*)d_in[7];
    const float* b_2  = (const float*)d_in[8];
    float* out = (float*)d_out;

    const int B = 2, N = 30000;
    const int S1 = 56, S3 = 28;        // K-steps: 1792/32, 896/32
    const int NBLK = (N + 63) / 64;    // 469 conv blocks per batch

    char* ws = (char*)d_ws;
    size_t off = 0;
    auto alloc = [&](size_t bytes) {
        char* p = ws + off;
        off += (bytes + 255) & ~(size_t)255;
        return p;
    };
    unsigned short* upT   = (unsigned short*)alloc((size_t)B * N * 256 * 2);
    unsigned short* catT  = (unsigned short*)alloc((size_t)B * N * 256 * 2);
    unsigned short* x1    = (unsigned short*)alloc((size_t)B * N * 128 * 2);
    unsigned short* Wp0   = (unsigned short*)alloc((size_t)S1 * 512 * 8 * 2);
    unsigned short* Wp1   = (unsigned short*)alloc((size_t)S1 * 512 * 8 * 2);
    unsigned short* Wp2b  = (unsigned short*)alloc((size_t)B * S3 * 512 * 8 * 2);
    float*  b2fold = (float*)alloc((size_t)B * 128 * 4);
    float2* part   = (float2*)alloc((size_t)B * NBLK * 128 * 8);
    float2* stats1 = (float2*)alloc((size_t)B * 128 * 8);
    float2* stats2 = (float2*)alloc((size_t)B * 128 * 8);
    unsigned short* zbuf = upT;  // reuse (upT dead after conv1)

    // prepack static weights
    prepack_w<<<(S1 * 512 + 255) / 256, 256, 0, stream>>>(W_up, Wp0, 256, S1);
    prepack_w<<<(S1 * 512 + 255) / 256, 256, 0, stream>>>(W_1,  Wp1, 256, S1);

    // transpose inputs to [B][N][C] bf16
    dim3 tb(32, 8);
    transpose_cast<<<dim3((N + 31) / 32, 256 / 32, B), tb, 0, stream>>>(from_up, upT, 256, N, 256, 0);
    transpose_cast<<<dim3((N + 31) / 32, 128 / 32, B), tb, 0, stream>>>(from_down, catT, 128, N, 256, 128);

    dim3 cgrid(NBLK, B);
    // conv1: upT (Cin=256) -> catT[:, 0:128]
    conv_mfma<256, 256, false><<<cgrid, 256, 0, stream>>>(
        upT, neighbors, Wp0, 0, b_up, 0, catT, nullptr, N, 0);
    // conv2: catT (Cin=256) -> x1, fused stats partials
    conv_mfma<256, 128, true><<<cgrid, 256, 0, stream>>>(
        catT, neighbors, Wp1, 0, b_1, 0, x1, part, N, 0);
    stats_final<<<B, 128, 0, stream>>>((const float2*)part, stats1, N, NBLK);

    // fold norm1 into conv3's weights/bias (per batch)
    prepack_w_scaled<<<(B * S3 * 512 + 255) / 256, 256, 0, stream>>>(W_2, stats1, Wp2b, 128, S3);
    fold_bias2<<<B, 128, 0, stream>>>(W_2, b_2, stats1, b2fold);

    // conv3: x1 (Cin=128, scaled weights) -> zbuf, fused stats partials
    conv_mfma<128, 128, true><<<cgrid, 256, 0, stream>>>(
        x1, neighbors, Wp2b, (size_t)S3 * 512, b2fold, 128, zbuf, part, N, 0);
    stats_final<<<B, 128, 0, stream>>>((const float2*)part, stats2, N, NBLK);

    // final: normalize z, add recomputed x1n, transpose to [B][128][N] fp32
    final_k<<<dim3((N + 31) / 32, 4, B), tb, 0, stream>>>(zbuf, x1, stats1, stats2, out, N);
}

// Round 4
// 301.450 us; speedup vs baseline: 1.6956x; 1.6956x over previous
//
#include <hip/hip_runtime.h>

typedef __attribute__((ext_vector_type(8))) short short8;
typedef __attribute__((ext_vector_type(4))) float f32x4;

static __device__ __forceinline__ float bf2f(unsigned short u) {
    unsigned int x = ((unsigned int)u) << 16;
    union { unsigned int i; float f; } c; c.i = x; return c.f;
}
static __device__ __forceinline__ unsigned short f2bf(float f) {
    union { float f; unsigned int i; } c; c.f = f;
    unsigned int x = c.i;
    unsigned int r = (x + 0x7FFFu + ((x >> 16) & 1u)) >> 16;
    return (unsigned short)r;
}

// ---------------- prepack W [Cout=128][Cin][7] fp32 -> fragment-linear bf16 ----------------
// Wp[( (s*8 + f)*64 + lane )*8 + j] = W[o = f*16+(lane&15)][c = kk%Cin][t = kk/Cin],
// kk = s*32 + 8*(lane>>4) + j
__global__ void prepack_w(const float* __restrict__ W, unsigned short* __restrict__ Wp,
                          int Cin, int S) {
    int tid = blockIdx.x * blockDim.x + threadIdx.x;
    if (tid >= S * 512) return;
    int lane = tid & 63;
    int f = (tid >> 6) & 7;
    int s = tid >> 9;
    int o = f * 16 + (lane & 15);
    int kbase = s * 32 + 8 * (lane >> 4);
    unsigned short* dst = Wp + (size_t)tid * 8;
#pragma unroll
    for (int j = 0; j < 8; ++j) {
        int kk = kbase + j;
        int t = kk / Cin;
        int c = kk - t * Cin;
        dst[j] = f2bf(W[((size_t)o * Cin + c) * 7 + t]);
    }
}

// Same but scales W[o][c][t] by rstd[b][c] (norm folded into conv3), one copy per batch.
__global__ void prepack_w_scaled(const float* __restrict__ W, const float2* __restrict__ stats,
                                 unsigned short* __restrict__ Wp, int Cin, int S) {
    int tid = blockIdx.x * blockDim.x + threadIdx.x;
    if (tid >= 2 * S * 512) return;
    int b = tid / (S * 512);
    int rem = tid - b * S * 512;
    int lane = rem & 63;
    int f = (rem >> 6) & 7;
    int s = rem >> 9;
    int o = f * 16 + (lane & 15);
    int kbase = s * 32 + 8 * (lane >> 4);
    unsigned short* dst = Wp + (size_t)tid * 8;
#pragma unroll
    for (int j = 0; j < 8; ++j) {
        int kk = kbase + j;
        int t = kk / Cin;
        int c = kk - t * Cin;
        float scale = stats[b * 128 + c].y;
        dst[j] = f2bf(W[((size_t)o * Cin + c) * 7 + t] * scale);
    }
}

// b2'[b][o] = b2[o] - sum_{c,t} W2[o][c][t] * rstd[b][c] * mu[b][c]
__global__ void fold_bias2(const float* __restrict__ W2, const float* __restrict__ b2,
                           const float2* __restrict__ stats, float* __restrict__ b2out) {
    int b = blockIdx.x, o = threadIdx.x;
    float sum = 0.f;
    for (int c = 0; c < 128; ++c) {
        float2 st = stats[b * 128 + c];
        float sm = st.x * st.y;
        float ws = 0.f;
#pragma unroll
        for (int t = 0; t < 7; ++t) ws += W2[((size_t)o * 128 + c) * 7 + t];
        sum += ws * sm;
    }
    b2out[b * 128 + o] = b2[o] - sum;
}

// ---------------- transpose fp32 [B][C][N] -> bf16 [B][N][ldo] at column offset ----------------
__global__ void transpose_cast(const float* __restrict__ in, unsigned short* __restrict__ out,
                               int C, int N, int ldo, int coff) {
    __shared__ float tile[32][33];
    int b = blockIdx.z;
    int n0 = blockIdx.x * 32;
    int c0 = blockIdx.y * 32;
    const float* inb = in + (size_t)b * C * N;
    unsigned short* outb = out + (size_t)b * N * ldo;
    int tx = threadIdx.x, ty = threadIdx.y;
#pragma unroll
    for (int i = 0; i < 32; i += 8) {
        int c = c0 + ty + i, n = n0 + tx;
        float v = 0.f;
        if (n < N) v = inb[(size_t)c * N + n];
        tile[ty + i][tx] = v;
    }
    __syncthreads();
#pragma unroll
    for (int i = 0; i < 32; i += 8) {
        int n = n0 + ty + i, c = c0 + tx;
        if (n < N) outb[(size_t)n * ldo + coff + c] = f2bf(tile[tx][ty + i]);
    }
}

// ---------------- gather-conv via MFMA, optional fused per-block stats ----------------
// Block: 64 points x 128 couts, 4 waves. Wave = 32 points (pg=wid&1) x 64 couts (h=wid>>1).
// Waves pg=0 (wid 0,2) gather the same rows -> L1/L2 sharing of the gather traffic.
template<int CS, int LD, bool STATS>
__global__ __launch_bounds__(256, 4) void conv_mfma(
    const unsigned short* __restrict__ src,
    const int* __restrict__ nbrs,
    const unsigned short* __restrict__ Wp, size_t w_bstride8,
    const float* __restrict__ bias, int bias_bstride,
    unsigned short* __restrict__ dst,
    float2* __restrict__ part,
    int N, int coff)
{
    const int lane = threadIdx.x & 63;
    const int wid  = threadIdx.x >> 6;
    const int pg   = wid & 1;    // point-group
    const int h    = wid >> 1;   // cout-half
    const int b    = blockIdx.y;
    const int p_base = blockIdx.x * 64 + pg * 32;
    const int l15 = lane & 15;
    const int ks  = lane >> 4;

    const unsigned short* srcb = src + (size_t)b * N * CS;
    // fold cout-half offset (h*4 f-frags * 64 lanes) into the W base
    const short8* wb = reinterpret_cast<const short8*>(Wp) + (size_t)b * w_bstride8 + (size_t)h * 256;
    const float* biasb = bias + (size_t)b * bias_bstride + h * 64;

    int idx0[7], idx1[7];
    {
        int p0 = p_base + l15;        int pe0 = p0 < N ? p0 : N - 1;
        int p1 = p_base + 16 + l15;   int pe1 = p1 < N ? p1 : N - 1;
        idx0[0] = pe0; idx1[0] = pe1;
        const int* nb0 = nbrs + ((size_t)b * N + pe0) * 6;
        const int* nb1 = nbrs + ((size_t)b * N + pe1) * 6;
#pragma unroll
        for (int t = 1; t < 7; ++t) { idx0[t] = nb0[t - 1]; idx1[t] = nb1[t - 1]; }
    }

    float bias_v[4];
#pragma unroll
    for (int fi = 0; fi < 4; ++fi) bias_v[fi] = biasb[fi * 16 + l15];

    f32x4 acc[2][4];
#pragma unroll
    for (int pf = 0; pf < 2; ++pf)
#pragma unroll
        for (int fi = 0; fi < 4; ++fi) acc[pf][fi] = (f32x4){0.f, 0.f, 0.f, 0.f};

    const int SPT = CS / 32;  // K-steps per tap
#pragma unroll
    for (int t = 0; t < 7; ++t) {
        const unsigned short* row0 = srcb + (size_t)idx0[t] * CS + 8 * ks;
        const unsigned short* row1 = srcb + (size_t)idx1[t] * CS + 8 * ks;
#pragma unroll
        for (int s2 = 0; s2 < SPT; ++s2) {
            const int s = t * SPT + s2;
            short8 a0 = *reinterpret_cast<const short8*>(row0 + s2 * 32);
            short8 a1 = *reinterpret_cast<const short8*>(row1 + s2 * 32);
            const short8* wbase = wb + ((size_t)s * 512 + lane);
#pragma unroll
            for (int fi = 0; fi < 4; ++fi) {
                short8 bfv = wbase[fi * 64];
                acc[0][fi] = __builtin_amdgcn_mfma_f32_16x16x32_bf16(a0, bfv, acc[0][fi], 0, 0, 0);
                acc[1][fi] = __builtin_amdgcn_mfma_f32_16x16x32_bf16(a1, bfv, acc[1][fi], 0, 0, 0);
            }
        }
    }

    unsigned short* dstb = dst + (size_t)b * N * LD + coff + h * 64;
#pragma unroll
    for (int pf = 0; pf < 2; ++pf) {
#pragma unroll
        for (int r = 0; r < 4; ++r) {
            int p = p_base + pf * 16 + ks * 4 + r;
            if (p < N) {
#pragma unroll
                for (int fi = 0; fi < 4; ++fi) {
                    dstb[(size_t)p * LD + fi * 16 + l15] = f2bf(acc[pf][fi][r] + bias_v[fi]);
                }
            }
        }
    }

    if constexpr (STATS) {
        float s[4], q[4];
#pragma unroll
        for (int fi = 0; fi < 4; ++fi) { s[fi] = 0.f; q[fi] = 0.f; }
#pragma unroll
        for (int pf = 0; pf < 2; ++pf) {
#pragma unroll
            for (int r = 0; r < 4; ++r) {
                int p = p_base + pf * 16 + ks * 4 + r;
                if (p < N) {
#pragma unroll
                    for (int fi = 0; fi < 4; ++fi) {
                        float v = acc[pf][fi][r] + bias_v[fi];
                        s[fi] += v; q[fi] += v * v;
                    }
                }
            }
        }
        // combine the 4 ks-groups (different points, same channels)
#pragma unroll
        for (int fi = 0; fi < 4; ++fi) {
            s[fi] += __shfl_xor(s[fi], 16); s[fi] += __shfl_xor(s[fi], 32);
            q[fi] += __shfl_xor(q[fi], 16); q[fi] += __shfl_xor(q[fi], 32);
        }
        __shared__ float shs[4][64], shq[4][64];
        if (lane < 16) {
#pragma unroll
            for (int fi = 0; fi < 4; ++fi) {
                shs[wid][fi * 16 + l15] = s[fi];
                shq[wid][fi * 16 + l15] = q[fi];
            }
        }
        __syncthreads();
        if (threadIdx.x < 128) {
            int c = threadIdx.x;          // channel 0..127
            int hh = c >> 6, cl = c & 63; // waves 2*hh and 2*hh+1 hold this channel-half
            float ss = shs[2 * hh][cl] + shs[2 * hh + 1][cl];
            float qq = shq[2 * hh][cl] + shq[2 * hh + 1][cl];
            part[((size_t)b * gridDim.x + blockIdx.x) * 128 + c] = make_float2(ss, qq);
        }
    }
}

// ---------------- final reduce of per-block partials -> (mu, rstd) ----------------
// 1024 threads: r = tid>>7 (8 row-groups), c = tid&127. Coalesced over c.
__global__ void stats_final(const float2* __restrict__ part, float2* __restrict__ stats,
                            int N, int NB) {
    int b = blockIdx.x;
    int c = threadIdx.x & 127;
    int r = threadIdx.x >> 7;  // 0..7
    float s = 0.f, sq = 0.f;
    const float2* p = part + (size_t)b * NB * 128 + c;
#pragma unroll 4
    for (int i = r; i < NB; i += 8) {
        float2 v = p[(size_t)i * 128];
        s += v.x; sq += v.y;
    }
    __shared__ float shs[8][128], shq[8][128];
    shs[r][c] = s; shq[r][c] = sq;
    __syncthreads();
    if (r == 0) {
#pragma unroll
        for (int i = 1; i < 8; ++i) { s += shs[i][c]; sq += shq[i][c]; }
        float mu = s / N;
        float var = sq / N - mu * mu;
        stats[b * 128 + c] = make_float2(mu, rsqrtf(var + 1e-5f));
    }
}

// ---------------- final: out[b][o][n] = (z-mu2)*rstd2 + (x1-mu1)*rstd1, fp32 transposed ----------------
__global__ void final_k(const unsigned short* __restrict__ z, const unsigned short* __restrict__ x1,
                        const float2* __restrict__ stats1, const float2* __restrict__ stats2,
                        float* __restrict__ out, int N) {
    __shared__ float tile[32][33];
    int b = blockIdx.z;
    int n0 = blockIdx.x * 32, o0 = blockIdx.y * 32;
    int tx = threadIdx.x, ty = threadIdx.y;
    const unsigned short* zb = z  + (size_t)b * N * 128;
    const unsigned short* xb = x1 + (size_t)b * N * 128;
    float2 st1 = stats1[b * 128 + o0 + tx];
    float2 st2 = stats2[b * 128 + o0 + tx];
#pragma unroll
    for (int i = 0; i < 32; i += 8) {
        int n = n0 + ty + i;
        float v = 0.f;
        if (n < N) {
            float zv = bf2f(zb[(size_t)n * 128 + o0 + tx]);
            float xv = bf2f(xb[(size_t)n * 128 + o0 + tx]);
            v = (zv - st2.x) * st2.y + (xv - st1.x) * st1.y;
        }
        tile[ty + i][tx] = v;
    }
    __syncthreads();
    float* ob = out + (size_t)b * 128 * N;
#pragma unroll
    for (int i = 0; i < 32; i += 8) {
        int o = o0 + ty + i, n = n0 + tx;
        if (n < N) ob[(size_t)o * N + n] = tile[tx][ty + i];
    }
}

extern "C" void kernel_launch(void* const* d_in, const int* in_sizes, int n_in,
                              void* d_out, int out_size, void* d_ws, size_t ws_size,
                              hipStream_t stream) {
    const float* from_up   = (const float*)d_in[0];  // [2,256,30000]
    const float* from_down = (const float*)d_in[1];  // [2,128,30000]
    const int*   neighbors = (const int*)d_in[2];    // [2,30000,6]
    const float* W_up = (const float*)d_in[3];
    const float* b_up = (const float*)d_in[4];
    const float* W_1  = (const float*)d_in[5];
    const float* b_1  = (const float*)d_in[6];
    const float* W_2  = (const float*)d_in[7];
    const float* b_2  = (const float*)d_in[8];
    float* out = (float*)d_out;

    const int B = 2, N = 30000;
    const int S1 = 56, S3 = 28;        // K-steps: 1792/32, 896/32
    const int NBLK = (N + 63) / 64;    // 469 conv blocks per batch

    char* ws = (char*)d_ws;
    size_t off = 0;
    auto alloc = [&](size_t bytes) {
        char* p = ws + off;
        off += (bytes + 255) & ~(size_t)255;
        return p;
    };
    unsigned short* upT   = (unsigned short*)alloc((size_t)B * N * 256 * 2);
    unsigned short* catT  = (unsigned short*)alloc((size_t)B * N * 256 * 2);
    unsigned short* x1    = (unsigned short*)alloc((size_t)B * N * 128 * 2);
    unsigned short* Wp0   = (unsigned short*)alloc((size_t)S1 * 512 * 8 * 2);
    unsigned short* Wp1   = (unsigned short*)alloc((size_t)S1 * 512 * 8 * 2);
    unsigned short* Wp2b  = (unsigned short*)alloc((size_t)B * S3 * 512 * 8 * 2);
    float*  b2fold = (float*)alloc((size_t)B * 128 * 4);
    float2* part   = (float2*)alloc((size_t)B * NBLK * 128 * 8);
    float2* stats1 = (float2*)alloc((size_t)B * 128 * 8);
    float2* stats2 = (float2*)alloc((size_t)B * 128 * 8);
    unsigned short* zbuf = upT;  // reuse (upT dead after conv1)

    // prepack static weights
    prepack_w<<<(S1 * 512 + 255) / 256, 256, 0, stream>>>(W_up, Wp0, 256, S1);
    prepack_w<<<(S1 * 512 + 255) / 256, 256, 0, stream>>>(W_1,  Wp1, 256, S1);

    // transpose inputs to [B][N][C] bf16
    dim3 tb(32, 8);
    transpose_cast<<<dim3((N + 31) / 32, 256 / 32, B), tb, 0, stream>>>(from_up, upT, 256, N, 256, 0);
    transpose_cast<<<dim3((N + 31) / 32, 128 / 32, B), tb, 0, stream>>>(from_down, catT, 128, N, 256, 128);

    dim3 cgrid(NBLK, B);
    // conv1: upT (Cin=256) -> catT[:, 0:128]
    conv_mfma<256, 256, false><<<cgrid, 256, 0, stream>>>(
        upT, neighbors, Wp0, 0, b_up, 0, catT, nullptr, N, 0);
    // conv2: catT (Cin=256) -> x1, fused stats partials
    conv_mfma<256, 128, true><<<cgrid, 256, 0, stream>>>(
        catT, neighbors, Wp1, 0, b_1, 0, x1, part, N, 0);
    stats_final<<<B, 1024, 0, stream>>>((const float2*)part, stats1, N, NBLK);

    // fold norm1 into conv3's weights/bias (per batch)
    prepack_w_scaled<<<(B * S3 * 512 + 255) / 256, 256, 0, stream>>>(W_2, stats1, Wp2b, 128, S3);
    fold_bias2<<<B, 128, 0, stream>>>(W_2, b_2, stats1, b2fold);

    // conv3: x1 (Cin=128, scaled weights) -> zbuf, fused stats partials
    conv_mfma<128, 128, true><<<cgrid, 256, 0, stream>>>(
        x1, neighbors, Wp2b, (size_t)S3 * 512, b2fold, 128, zbuf, part, N, 0);
    stats_final<<<B, 1024, 0, stream>>>((const float2*)part, stats2, N, NBLK);

    // final: normalize z, add recomputed x1n, transpose to [B][128][N] fp32
    final_k<<<dim3((N + 31) / 32, 4, B), tb, 0, stream>>>(zbuf, x1, stats1, stats2, out, N);
}

// Round 5
// 295.067 us; speedup vs baseline: 1.7323x; 1.0216x over previous
//
#include <hip/hip_runtime.h>

typedef __attribute__((ext_vector_type(8))) short short8;
typedef __attribute__((ext_vector_type(4))) float f32x4;

static __device__ __forceinline__ float bf2f(unsigned short u) {
    unsigned int x = ((unsigned int)u) << 16;
    union { unsigned int i; float f; } c; c.i = x; return c.f;
}
static __device__ __forceinline__ unsigned short f2bf(float f) {
    union { float f; unsigned int i; } c; c.f = f;
    unsigned int x = c.i;
    unsigned int r = (x + 0x7FFFu + ((x >> 16) & 1u)) >> 16;
    return (unsigned short)r;
}

// ---------------- prepack W [Cout=128][Cin][7] fp32 -> fragment-linear bf16 ----------------
// Wp[( (s*8 + f)*64 + lane )*8 + j] = W[o = f*16+(lane&15)][c = kk%Cin][t = kk/Cin],
// kk = s*32 + 8*(lane>>4) + j
__global__ void prepack_w(const float* __restrict__ W, unsigned short* __restrict__ Wp,
                          int Cin, int S) {
    int tid = blockIdx.x * blockDim.x + threadIdx.x;
    if (tid >= S * 512) return;
    int lane = tid & 63;
    int f = (tid >> 6) & 7;
    int s = tid >> 9;
    int o = f * 16 + (lane & 15);
    int kbase = s * 32 + 8 * (lane >> 4);
    unsigned short* dst = Wp + (size_t)tid * 8;
#pragma unroll
    for (int j = 0; j < 8; ++j) {
        int kk = kbase + j;
        int t = kk / Cin;
        int c = kk - t * Cin;
        dst[j] = f2bf(W[((size_t)o * Cin + c) * 7 + t]);
    }
}

// Same but scales W[o][c][t] by rstd[b][c] (norm folded into conv3), one copy per batch.
__global__ void prepack_w_scaled(const float* __restrict__ W, const float2* __restrict__ stats,
                                 unsigned short* __restrict__ Wp, int Cin, int S) {
    int tid = blockIdx.x * blockDim.x + threadIdx.x;
    if (tid >= 2 * S * 512) return;
    int b = tid / (S * 512);
    int rem = tid - b * S * 512;
    int lane = rem & 63;
    int f = (rem >> 6) & 7;
    int s = rem >> 9;
    int o = f * 16 + (lane & 15);
    int kbase = s * 32 + 8 * (lane >> 4);
    unsigned short* dst = Wp + (size_t)tid * 8;
#pragma unroll
    for (int j = 0; j < 8; ++j) {
        int kk = kbase + j;
        int t = kk / Cin;
        int c = kk - t * Cin;
        float scale = stats[b * 128 + c].y;
        dst[j] = f2bf(W[((size_t)o * Cin + c) * 7 + t] * scale);
    }
}

// b2'[b][o] = b2[o] - sum_{c,t} W2[o][c][t] * rstd[b][c] * mu[b][c]
__global__ void fold_bias2(const float* __restrict__ W2, const float* __restrict__ b2,
                           const float2* __restrict__ stats, float* __restrict__ b2out) {
    int b = blockIdx.x, o = threadIdx.x;
    float sum = 0.f;
    for (int c = 0; c < 128; ++c) {
        float2 st = stats[b * 128 + c];
        float sm = st.x * st.y;
        float ws = 0.f;
#pragma unroll
        for (int t = 0; t < 7; ++t) ws += W2[((size_t)o * 128 + c) * 7 + t];
        sum += ws * sm;
    }
    b2out[b * 128 + o] = b2[o] - sum;
}

// ---------------- transpose fp32 [B][C][N] -> bf16 [B][N][ldo] at column offset ----------------
__global__ void transpose_cast(const float* __restrict__ in, unsigned short* __restrict__ out,
                               int C, int N, int ldo, int coff) {
    __shared__ float tile[32][33];
    int b = blockIdx.z;
    int n0 = blockIdx.x * 32;
    int c0 = blockIdx.y * 32;
    const float* inb = in + (size_t)b * C * N;
    unsigned short* outb = out + (size_t)b * N * ldo;
    int tx = threadIdx.x, ty = threadIdx.y;
#pragma unroll
    for (int i = 0; i < 32; i += 8) {
        int c = c0 + ty + i, n = n0 + tx;
        float v = 0.f;
        if (n < N) v = inb[(size_t)c * N + n];
        tile[ty + i][tx] = v;
    }
    __syncthreads();
#pragma unroll
    for (int i = 0; i < 32; i += 8) {
        int n = n0 + ty + i, c = c0 + tx;
        if (n < N) outb[(size_t)n * ldo + coff + c] = f2bf(tile[tx][ty + i]);
    }
}

// ---------------- gather-conv via MFMA, optional fused per-block stats ----------------
// Block: 128 points x 128 couts, 4 waves. Wave = 64 points (pg=wid&1) x 64 couts (h=wid>>1).
// 16 MFMAs per K-step; depth-3 register pipeline keeps ~16-24 loads in flight per wave.
template<int CS, int LD, bool STATS>
__global__ __launch_bounds__(256, 2) void conv_mfma(
    const unsigned short* __restrict__ src,
    const int* __restrict__ nbrs,
    const unsigned short* __restrict__ Wp, size_t w_bstride8,
    const float* __restrict__ bias, int bias_bstride,
    unsigned short* __restrict__ dst,
    float2* __restrict__ part,
    int N, int coff)
{
    const int lane = threadIdx.x & 63;
    const int wid  = threadIdx.x >> 6;
    const int pg   = wid & 1;    // point-group (64 points)
    const int h    = wid >> 1;   // cout-half
    const int b    = blockIdx.y;
    const int p_base = blockIdx.x * 128 + pg * 64;
    const int l15 = lane & 15;
    const int ks  = lane >> 4;

    const int SPT = CS / 32;   // K-steps per tap
    const int S   = SPT * 7;   // total K-steps

    const unsigned short* srcb = src + (size_t)b * N * CS;
    const short8* wb = reinterpret_cast<const short8*>(Wp) + (size_t)b * w_bstride8 + (size_t)h * 256;
    const float* biasb = bias + (size_t)b * bias_bstride + h * 64;

    // row offsets (in shorts) for 4 row-groups x 7 taps
    int offs[4][7];
#pragma unroll
    for (int rg = 0; rg < 4; ++rg) {
        int p = p_base + rg * 16 + l15;
        int pe = p < N ? p : N - 1;
        offs[rg][0] = pe * CS;
        const int* nb = nbrs + ((size_t)b * N + pe) * 6;
#pragma unroll
        for (int t = 1; t < 7; ++t) offs[rg][t] = nb[t - 1] * CS;
    }

    float bias_v[4];
#pragma unroll
    for (int fi = 0; fi < 4; ++fi) bias_v[fi] = biasb[fi * 16 + l15];

    f32x4 acc[4][4];
#pragma unroll
    for (int rg = 0; rg < 4; ++rg)
#pragma unroll
        for (int fi = 0; fi < 4; ++fi) acc[rg][fi] = (f32x4){0.f, 0.f, 0.f, 0.f};

    auto loadStep = [&](int s, short8 A[4], short8 Wl[4]) {
        int t = s / SPT, kk = s - t * SPT;
#pragma unroll
        for (int rg = 0; rg < 4; ++rg)
            A[rg] = *reinterpret_cast<const short8*>(srcb + offs[rg][t] + kk * 32 + 8 * ks);
        const short8* wrow = wb + (size_t)s * 512 + lane;
#pragma unroll
        for (int fi = 0; fi < 4; ++fi) Wl[fi] = wrow[fi * 64];
    };
    auto compute = [&](short8 A[4], short8 Wl[4]) {
#pragma unroll
        for (int rg = 0; rg < 4; ++rg)
#pragma unroll
            for (int fi = 0; fi < 4; ++fi)
                acc[rg][fi] = __builtin_amdgcn_mfma_f32_16x16x32_bf16(A[rg], Wl[fi], acc[rg][fi], 0, 0, 0);
    };

    short8 A0[4], W0[4], A1[4], W1[4], A2[4], W2r[4];
    loadStep(0, A0, W0);
    loadStep(1, A1, W1);
    loadStep(2, A2, W2r);
#pragma unroll
    for (int sb = 0; sb < S; sb += 3) {
        compute(A0, W0);
        if (sb + 3 < S) loadStep(sb + 3, A0, W0);
        if (sb + 1 < S) {
            compute(A1, W1);
            if (sb + 4 < S) loadStep(sb + 4, A1, W1);
        }
        if (sb + 2 < S) {
            compute(A2, W2r);
            if (sb + 5 < S) loadStep(sb + 5, A2, W2r);
        }
    }

    unsigned short* dstb = dst + (size_t)b * N * LD + coff + h * 64;
#pragma unroll
    for (int rg = 0; rg < 4; ++rg) {
#pragma unroll
        for (int r = 0; r < 4; ++r) {
            int p = p_base + rg * 16 + ks * 4 + r;
            if (p < N) {
#pragma unroll
                for (int fi = 0; fi < 4; ++fi) {
                    dstb[(size_t)p * LD + fi * 16 + l15] = f2bf(acc[rg][fi][r] + bias_v[fi]);
                }
            }
        }
    }

    if constexpr (STATS) {
        float s4[4], q4[4];
#pragma unroll
        for (int fi = 0; fi < 4; ++fi) { s4[fi] = 0.f; q4[fi] = 0.f; }
#pragma unroll
        for (int rg = 0; rg < 4; ++rg) {
#pragma unroll
            for (int r = 0; r < 4; ++r) {
                int p = p_base + rg * 16 + ks * 4 + r;
                if (p < N) {
#pragma unroll
                    for (int fi = 0; fi < 4; ++fi) {
                        float v = acc[rg][fi][r] + bias_v[fi];
                        s4[fi] += v; q4[fi] += v * v;
                    }
                }
            }
        }
        // combine the 4 ks-groups (different points, same channels)
#pragma unroll
        for (int fi = 0; fi < 4; ++fi) {
            s4[fi] += __shfl_xor(s4[fi], 16); s4[fi] += __shfl_xor(s4[fi], 32);
            q4[fi] += __shfl_xor(q4[fi], 16); q4[fi] += __shfl_xor(q4[fi], 32);
        }
        __shared__ float shs[4][64], shq[4][64];
        if (lane < 16) {
#pragma unroll
            for (int fi = 0; fi < 4; ++fi) {
                shs[wid][fi * 16 + l15] = s4[fi];
                shq[wid][fi * 16 + l15] = q4[fi];
            }
        }
        __syncthreads();
        if (threadIdx.x < 128) {
            int c = threadIdx.x;          // channel 0..127
            int hh = c >> 6, cl = c & 63; // waves 2*hh (pg=0) and 2*hh+1 (pg=1) hold this half
            float ss = shs[2 * hh][cl] + shs[2 * hh + 1][cl];
            float qq = shq[2 * hh][cl] + shq[2 * hh + 1][cl];
            part[((size_t)b * gridDim.x + blockIdx.x) * 128 + c] = make_float2(ss, qq);
        }
    }
}

// ---------------- final reduce of per-block partials -> (mu, rstd) ----------------
// 1024 threads: r = tid>>7 (8 row-groups), c = tid&127. Coalesced over c.
__global__ void stats_final(const float2* __restrict__ part, float2* __restrict__ stats,
                            int N, int NB) {
    int b = blockIdx.x;
    int c = threadIdx.x & 127;
    int r = threadIdx.x >> 7;  // 0..7
    float s = 0.f, sq = 0.f;
    const float2* p = part + (size_t)b * NB * 128 + c;
#pragma unroll 4
    for (int i = r; i < NB; i += 8) {
        float2 v = p[(size_t)i * 128];
        s += v.x; sq += v.y;
    }
    __shared__ float shs[8][128], shq[8][128];
    shs[r][c] = s; shq[r][c] = sq;
    __syncthreads();
    if (r == 0) {
#pragma unroll
        for (int i = 1; i < 8; ++i) { s += shs[i][c]; sq += shq[i][c]; }
        float mu = s / N;
        float var = sq / N - mu * mu;
        stats[b * 128 + c] = make_float2(mu, rsqrtf(var + 1e-5f));
    }
}

// ---------------- final: out[b][o][n] = (z-mu2)*rstd2 + (x1-mu1)*rstd1, fp32 transposed ----------------
__global__ void final_k(const unsigned short* __restrict__ z, const unsigned short* __restrict__ x1,
                        const float2* __restrict__ stats1, const float2* __restrict__ stats2,
                        float* __restrict__ out, int N) {
    __shared__ float tile[32][33];
    int b = blockIdx.z;
    int n0 = blockIdx.x * 32, o0 = blockIdx.y * 32;
    int tx = threadIdx.x, ty = threadIdx.y;
    const unsigned short* zb = z  + (size_t)b * N * 128;
    const unsigned short* xb = x1 + (size_t)b * N * 128;
    float2 st1 = stats1[b * 128 + o0 + tx];
    float2 st2 = stats2[b * 128 + o0 + tx];
#pragma unroll
    for (int i = 0; i < 32; i += 8) {
        int n = n0 + ty + i;
        float v = 0.f;
        if (n < N) {
            float zv = bf2f(zb[(size_t)n * 128 + o0 + tx]);
            float xv = bf2f(xb[(size_t)n * 128 + o0 + tx]);
            v = (zv - st2.x) * st2.y + (xv - st1.x) * st1.y;
        }
        tile[ty + i][tx] = v;
    }
    __syncthreads();
    float* ob = out + (size_t)b * 128 * N;
#pragma unroll
    for (int i = 0; i < 32; i += 8) {
        int o = o0 + ty + i, n = n0 + tx;
        if (n < N) ob[(size_t)o * N + n] = tile[tx][ty + i];
    }
}

extern "C" void kernel_launch(void* const* d_in, const int* in_sizes, int n_in,
                              void* d_out, int out_size, void* d_ws, size_t ws_size,
                              hipStream_t stream) {
    const float* from_up   = (const float*)d_in[0];  // [2,256,30000]
    const float* from_down = (const float*)d_in[1];  // [2,128,30000]
    const int*   neighbors = (const int*)d_in[2];    // [2,30000,6]
    const float* W_up = (const float*)d_in[3];
    const float* b_up = (const float*)d_in[4];
    const float* W_1  = (const float*)d_in[5];
    const float* b_1  = (const float*)d_in[6];
    const float* W_2  = (const float*)d_in[7];
    const float* b_2  = (const float*)d_in[8];
    float* out = (float*)d_out;

    const int B = 2, N = 30000;
    const int S1 = 56, S3 = 28;        // K-steps: 1792/32, 896/32
    const int NBLK = (N + 127) / 128;  // 235 conv blocks per batch

    char* ws = (char*)d_ws;
    size_t off = 0;
    auto alloc = [&](size_t bytes) {
        char* p = ws + off;
        off += (bytes + 255) & ~(size_t)255;
        return p;
    };
    unsigned short* upT   = (unsigned short*)alloc((size_t)B * N * 256 * 2);
    unsigned short* catT  = (unsigned short*)alloc((size_t)B * N * 256 * 2);
    unsigned short* x1    = (unsigned short*)alloc((size_t)B * N * 128 * 2);
    unsigned short* Wp0   = (unsigned short*)alloc((size_t)S1 * 512 * 8 * 2);
    unsigned short* Wp1   = (unsigned short*)alloc((size_t)S1 * 512 * 8 * 2);
    unsigned short* Wp2b  = (unsigned short*)alloc((size_t)B * S3 * 512 * 8 * 2);
    float*  b2fold = (float*)alloc((size_t)B * 128 * 4);
    float2* part   = (float2*)alloc((size_t)B * NBLK * 128 * 8);
    float2* stats1 = (float2*)alloc((size_t)B * 128 * 8);
    float2* stats2 = (float2*)alloc((size_t)B * 128 * 8);
    unsigned short* zbuf = upT;  // reuse (upT dead after conv1)

    // prepack static weights
    prepack_w<<<(S1 * 512 + 255) / 256, 256, 0, stream>>>(W_up, Wp0, 256, S1);
    prepack_w<<<(S1 * 512 + 255) / 256, 256, 0, stream>>>(W_1,  Wp1, 256, S1);

    // transpose inputs to [B][N][C] bf16
    dim3 tb(32, 8);
    transpose_cast<<<dim3((N + 31) / 32, 256 / 32, B), tb, 0, stream>>>(from_up, upT, 256, N, 256, 0);
    transpose_cast<<<dim3((N + 31) / 32, 128 / 32, B), tb, 0, stream>>>(from_down, catT, 128, N, 256, 128);

    dim3 cgrid(NBLK, B);
    // conv1: upT (Cin=256) -> catT[:, 0:128]
    conv_mfma<256, 256, false><<<cgrid, 256, 0, stream>>>(
        upT, neighbors, Wp0, 0, b_up, 0, catT, nullptr, N, 0);
    // conv2: catT (Cin=256) -> x1, fused stats partials
    conv_mfma<256, 128, true><<<cgrid, 256, 0, stream>>>(
        catT, neighbors, Wp1, 0, b_1, 0, x1, part, N, 0);
    stats_final<<<B, 1024, 0, stream>>>((const float2*)part, stats1, N, NBLK);

    // fold norm1 into conv3's weights/bias (per batch)
    prepack_w_scaled<<<(B * S3 * 512 + 255) / 256, 256, 0, stream>>>(W_2, stats1, Wp2b, 128, S3);
    fold_bias2<<<B, 128, 0, stream>>>(W_2, b_2, stats1, b2fold);

    // conv3: x1 (Cin=128, scaled weights) -> zbuf, fused stats partials
    conv_mfma<128, 128, true><<<cgrid, 256, 0, stream>>>(
        x1, neighbors, Wp2b, (size_t)S3 * 512, b2fold, 128, zbuf, part, N, 0);
    stats_final<<<B, 1024, 0, stream>>>((const float2*)part, stats2, N, NBLK);

    // final: normalize z, add recomputed x1n, transpose to [B][128][N] fp32
    final_k<<<dim3((N + 31) / 32, 4, B), tb, 0, stream>>>(zbuf, x1, stats1, stats2, out, N);
}